// Round 1
// baseline (954.558 us; speedup 1.0000x reference)
//
#include <hip/hip_runtime.h>
#include <hip/hip_bf16.h>
#include <math.h>

typedef __attribute__((ext_vector_type(8))) short bf16x8;
typedef __attribute__((ext_vector_type(4))) float f32x4;

#define B_ 2
#define S_ 2048
#define H_ 32
#define KVH_ 8
#define D_ 128
#define BM 64
#define BN 64
#define NQT (S_ / BM)
#define LDK 136   // K LDS row stride (shorts): 272B, 16B-aligned, 2-way banks (free)
#define LDV 72    // Vt LDS row stride (shorts): 144B, 16B-aligned
#define LDP 72    // P LDS row stride

__device__ __forceinline__ unsigned short f2bf(float x) {
    unsigned int u = __float_as_uint(x);
    u += 0x7FFFu + ((u >> 16) & 1u);   // round-to-nearest-even
    return (unsigned short)(u >> 16);
}

__global__ __launch_bounds__(256) void fa_fwd(
    const float* __restrict__ q, const float* __restrict__ k,
    const float* __restrict__ v, float* __restrict__ out)
{
    __shared__ short lds_k[BN * LDK];      // 17408 B
    __shared__ short lds_vt[D_ * LDV];     // 18432 B, V transposed (d, t)
    __shared__ short lds_p[4 * 16 * LDP];  // 9216 B, per-wave P tiles

    const int qt   = (NQT - 1) - blockIdx.x;   // heavy q-tiles first (LPT)
    const int h    = blockIdx.y;
    const int b    = blockIdx.z;
    const int kvh  = h >> 2;                   // N_REP = 4
    const int tid  = threadIdx.x;
    const int wave = tid >> 6;
    const int lane = tid & 63;
    const int quad = lane >> 4;
    const int l16  = lane & 15;
    const int s0   = qt * BM;

    // ---- Q fragments in registers (A-layout: m = l16, k = quad*8 + j) ----
    const int sq = s0 + wave * 16 + l16;
    const float* qrow = q + (size_t)((b * S_ + sq) * H_ + h) * D_;
    bf16x8 qf[4];
    #pragma unroll
    for (int c = 0; c < 4; ++c) {
        const float* p = qrow + c * 32 + quad * 8;
        float4 a0 = *(const float4*)(p);
        float4 a1 = *(const float4*)(p + 4);
        qf[c][0] = (short)f2bf(a0.x); qf[c][1] = (short)f2bf(a0.y);
        qf[c][2] = (short)f2bf(a0.z); qf[c][3] = (short)f2bf(a0.w);
        qf[c][4] = (short)f2bf(a1.x); qf[c][5] = (short)f2bf(a1.y);
        qf[c][6] = (short)f2bf(a1.z); qf[c][7] = (short)f2bf(a1.w);
    }

    f32x4 o[8];
    #pragma unroll
    for (int n = 0; n < 8; ++n) o[n] = (f32x4){0.f, 0.f, 0.f, 0.f};
    float Mr[4] = {-1e30f, -1e30f, -1e30f, -1e30f};
    float Lr[4] = {0.f, 0.f, 0.f, 0.f};

    const float sl2e = 0.08838834764831843f * 1.4426950408889634f; // scale*log2(e)

    const float* kb = k + (size_t)(b * KVH_ + kvh) * S_ * D_;
    const float* vb = v + (size_t)(b * KVH_ + kvh) * S_ * D_;
    short* pw = &lds_p[wave * 16 * LDP];

    for (int ti = 0; ti <= qt; ++ti) {
        __syncthreads();   // prev iter's LDS reads done before restage
        // ---- stage K (row-major bf16) + V (transposed bf16) ----
        const float* kt = kb + ti * BN * D_;
        const float* vt = vb + ti * BN * D_;
        #pragma unroll
        for (int it = 0; it < 8; ++it) {
            const int idx = it * 256 + tid;
            const int t = idx >> 5;
            const int c = (idx & 31) << 2;
            float4 f = *(const float4*)(kt + t * D_ + c);
            ushort4 u;
            u.x = f2bf(f.x); u.y = f2bf(f.y); u.z = f2bf(f.z); u.w = f2bf(f.w);
            *(ushort4*)(&lds_k[t * LDK + c]) = u;
        }
        #pragma unroll
        for (int it = 0; it < 8; ++it) {
            const int idx = it * 256 + tid;
            const int t = idx >> 5;
            const int c = (idx & 31) << 2;
            float4 f = *(const float4*)(vt + t * D_ + c);
            lds_vt[(c + 0) * LDV + t] = (short)f2bf(f.x);
            lds_vt[(c + 1) * LDV + t] = (short)f2bf(f.y);
            lds_vt[(c + 2) * LDV + t] = (short)f2bf(f.z);
            lds_vt[(c + 3) * LDV + t] = (short)f2bf(f.w);
        }
        __syncthreads();

        // ---- S = Q K^T (C-layout: col = l16 (key), row = quad*4 + r (query)) ----
        f32x4 sc[4];
        #pragma unroll
        for (int blk = 0; blk < 4; ++blk) sc[blk] = (f32x4){0.f, 0.f, 0.f, 0.f};
        #pragma unroll
        for (int blk = 0; blk < 4; ++blk) {
            #pragma unroll
            for (int c = 0; c < 4; ++c) {
                bf16x8 kf = *(const bf16x8*)(&lds_k[(blk * 16 + l16) * LDK + c * 32 + quad * 8]);
                sc[blk] = __builtin_amdgcn_mfma_f32_16x16x32_bf16(qf[c], kf, sc[blk], 0, 0, 0);
            }
        }

        // ---- online softmax (exp2 units) ----
        const bool diag = (ti == qt);
        #pragma unroll
        for (int blk = 0; blk < 4; ++blk) {
            #pragma unroll
            for (int r = 0; r < 4; ++r) {
                float z = sc[blk][r] * sl2e;
                if (diag) {
                    const int tcol = ti * BN + blk * 16 + l16;
                    const int srow = s0 + wave * 16 + quad * 4 + r;
                    if (tcol > srow) z = -1e30f;
                }
                sc[blk][r] = z;
            }
        }
        float mnew[4], alpha[4];
        #pragma unroll
        for (int r = 0; r < 4; ++r) {
            float m = fmaxf(fmaxf(sc[0][r], sc[1][r]), fmaxf(sc[2][r], sc[3][r]));
            m = fmaxf(m, __shfl_xor(m, 1, 16));
            m = fmaxf(m, __shfl_xor(m, 2, 16));
            m = fmaxf(m, __shfl_xor(m, 4, 16));
            m = fmaxf(m, __shfl_xor(m, 8, 16));
            mnew[r]  = fmaxf(Mr[r], m);
            alpha[r] = exp2f(Mr[r] - mnew[r]);
            Mr[r]    = mnew[r];
        }
        #pragma unroll
        for (int blk = 0; blk < 4; ++blk) {
            #pragma unroll
            for (int r = 0; r < 4; ++r)
                sc[blk][r] = exp2f(sc[blk][r] - mnew[r]);
        }
        #pragma unroll
        for (int r = 0; r < 4; ++r)
            Lr[r] = Lr[r] * alpha[r] + (sc[0][r] + sc[1][r] + sc[2][r] + sc[3][r]);
        // P -> wave-private LDS (C-layout write, A-layout read)
        #pragma unroll
        for (int blk = 0; blk < 4; ++blk) {
            #pragma unroll
            for (int r = 0; r < 4; ++r)
                pw[(quad * 4 + r) * LDP + blk * 16 + l16] = (short)f2bf(sc[blk][r]);
        }
        #pragma unroll
        for (int n = 0; n < 8; ++n) {
            #pragma unroll
            for (int r = 0; r < 4; ++r) o[n][r] *= alpha[r];
        }
        __syncthreads();   // P visible (and uniform barrier count)

        // ---- O += P V ----
        #pragma unroll
        for (int kk = 0; kk < 2; ++kk) {
            bf16x8 pf = *(const bf16x8*)(&pw[l16 * LDP + kk * 32 + quad * 8]);
            #pragma unroll
            for (int n = 0; n < 8; ++n) {
                bf16x8 vf = *(const bf16x8*)(&lds_vt[(n * 16 + l16) * LDV + kk * 32 + quad * 8]);
                o[n] = __builtin_amdgcn_mfma_f32_16x16x32_bf16(pf, vf, o[n], 0, 0, 0);
            }
        }
    }

    // ---- epilogue: 1/l and store ----
    #pragma unroll
    for (int r = 0; r < 4; ++r) {
        float l = Lr[r];
        l += __shfl_xor(l, 1, 16);
        l += __shfl_xor(l, 2, 16);
        l += __shfl_xor(l, 4, 16);
        l += __shfl_xor(l, 8, 16);
        Lr[r] = 1.0f / l;
    }
    #pragma unroll
    for (int r = 0; r < 4; ++r) {
        const int srow = s0 + wave * 16 + quad * 4 + r;
        float* orow = out + (size_t)(b * S_ + srow) * (H_ * D_) + h * D_;
        #pragma unroll
        for (int n = 0; n < 8; ++n)
            orow[n * 16 + l16] = o[n][r] * Lr[r];
    }
}

extern "C" void kernel_launch(void* const* d_in, const int* in_sizes, int n_in,
                              void* d_out, int out_size, void* d_ws, size_t ws_size,
                              hipStream_t stream) {
    // setup_inputs order: input_pos, q, k, v, bsz, seqlen, mask, cache_k, cache_v
    const float* q = (const float*)d_in[1];
    const float* k = (const float*)d_in[2];
    const float* v = (const float*)d_in[3];
    float* out = (float*)d_out;
    dim3 grid(NQT, H_, B_);
    fa_fwd<<<grid, 256, 0, stream>>>(q, k, v, out);
}

// Round 2
// 466.254 us; speedup vs baseline: 2.0473x; 2.0473x over previous
//
#include <hip/hip_runtime.h>
#include <hip/hip_bf16.h>

typedef __attribute__((ext_vector_type(8))) short bf16x8;
typedef __attribute__((ext_vector_type(4))) float f32x4;

#define B_ 2
#define S_ 2048
#define H_ 32
#define KVH_ 8
#define D_ 128
#define BM 128
#define BN 64
#define NQT (S_ / BM)   // 16
#define LDK 136   // K tile LDS row stride (shorts)
#define LDV 72    // V^T tile LDS row stride
#define LDP 72    // P tile LDS row stride

__device__ __forceinline__ unsigned short f2bf(float x) {
    unsigned int u = __float_as_uint(x);
    u += 0x7FFFu + ((u >> 16) & 1u);   // RNE
    return (unsigned short)(u >> 16);
}

// ---- pre-pass: K fp32 -> bf16 row-major in ws ----
__global__ __launch_bounds__(256) void conv_k(const float* __restrict__ k,
                                              short* __restrict__ kws) {
    const int idx = (blockIdx.x * 256 + threadIdx.x) * 8;
    float4 a0 = *(const float4*)(k + idx);
    float4 a1 = *(const float4*)(k + idx + 4);
    bf16x8 r;
    r[0] = (short)f2bf(a0.x); r[1] = (short)f2bf(a0.y);
    r[2] = (short)f2bf(a0.z); r[3] = (short)f2bf(a0.w);
    r[4] = (short)f2bf(a1.x); r[5] = (short)f2bf(a1.y);
    r[6] = (short)f2bf(a1.z); r[7] = (short)f2bf(a1.w);
    *(bf16x8*)(kws + idx) = r;
}

// ---- pre-pass: V fp32 [z][t][d] -> bf16 transposed [z][d][t] in ws ----
__global__ __launch_bounds__(256) void conv_vt(const float* __restrict__ v,
                                               short* __restrict__ vws) {
    __shared__ short tl[64 * 68];
    const int d0 = blockIdx.x * 64;
    const int t0 = blockIdx.y * 64;
    const int z  = blockIdx.z;
    const int tid = threadIdx.x;
    const float* vb = v + (size_t)z * S_ * D_;
    short* wb = vws + (size_t)z * D_ * S_;
    #pragma unroll
    for (int i = 0; i < 4; ++i) {
        const int chunk = i * 256 + tid;
        const int tr = chunk >> 4;
        const int c4 = (chunk & 15) << 2;
        float4 f = *(const float4*)(vb + (t0 + tr) * D_ + d0 + c4);
        ushort4 u;
        u.x = f2bf(f.x); u.y = f2bf(f.y); u.z = f2bf(f.z); u.w = f2bf(f.w);
        *(ushort4*)(&tl[tr * 68 + c4]) = u;
    }
    __syncthreads();
    #pragma unroll
    for (int i = 0; i < 2; ++i) {
        const int chunk = i * 256 + tid;
        const int d = chunk >> 3;
        const int tb = (chunk & 7) << 3;
        bf16x8 r;
        #pragma unroll
        for (int j = 0; j < 8; ++j) r[j] = tl[(tb + j) * 68 + d];
        *(bf16x8*)(wb + (size_t)(d0 + d) * S_ + t0 + tb) = r;
    }
}

// ---- main flash-attention kernel ----
__global__ __launch_bounds__(256, 2) void fa_fwd(
    const float* __restrict__ q, const short* __restrict__ kws,
    const short* __restrict__ vws, float* __restrict__ out)
{
    __shared__ short lds_k[BN * LDK];       // 17408 B
    __shared__ short lds_v[D_ * LDV];       // 18432 B (V^T: [d][t])
    __shared__ short lds_p[4 * 32 * LDP];   // 18432 B (per-wave 32x64 P)

    const int qt   = (NQT - 1) - blockIdx.x;   // heavy tiles first
    const int h    = blockIdx.y;
    const int b    = blockIdx.z;
    const int kvh  = h >> 2;
    const int tid  = threadIdx.x;
    const int wave = tid >> 6;
    const int lane = tid & 63;
    const int quad = lane >> 4;
    const int l16  = lane & 15;
    const int s0   = qt * BM;
    const int wr   = s0 + wave * 32;           // wave's first query row

    // Q fragments (A-layout), 2 M-blocks of 16 rows
    bf16x8 qf[2][4];
    #pragma unroll
    for (int mb = 0; mb < 2; ++mb) {
        const float* qrow = q + (size_t)((b * S_ + wr + mb * 16 + l16) * H_ + h) * D_;
        #pragma unroll
        for (int c = 0; c < 4; ++c) {
            const float* p = qrow + c * 32 + quad * 8;
            float4 a0 = *(const float4*)(p);
            float4 a1 = *(const float4*)(p + 4);
            qf[mb][c][0] = (short)f2bf(a0.x); qf[mb][c][1] = (short)f2bf(a0.y);
            qf[mb][c][2] = (short)f2bf(a0.z); qf[mb][c][3] = (short)f2bf(a0.w);
            qf[mb][c][4] = (short)f2bf(a1.x); qf[mb][c][5] = (short)f2bf(a1.y);
            qf[mb][c][6] = (short)f2bf(a1.z); qf[mb][c][7] = (short)f2bf(a1.w);
        }
    }

    f32x4 o[2][8];
    #pragma unroll
    for (int mb = 0; mb < 2; ++mb)
        #pragma unroll
        for (int db = 0; db < 8; ++db) o[mb][db] = (f32x4){0.f, 0.f, 0.f, 0.f};
    float Mr[2][4], Lr[2][4];
    #pragma unroll
    for (int mb = 0; mb < 2; ++mb)
        #pragma unroll
        for (int r = 0; r < 4; ++r) { Mr[mb][r] = -1e30f; Lr[mb][r] = 0.f; }

    const float sl2e = 0.08838834764831843f * 1.4426950408889634f;

    const short* kt = kws + (size_t)(b * KVH_ + kvh) * S_ * D_;
    const short* vt = vws + (size_t)(b * KVH_ + kvh) * D_ * S_;
    short* pw = &lds_p[wave * 32 * LDP];

    const int nt = 2 * qt + 2;
    // prefetch tile 0
    bf16x8 kpf[4], vpf[4];
    const short* kp = kt;
    const short* vp = vt;
    #pragma unroll
    for (int i = 0; i < 4; ++i) {
        const int ch = i * 256 + tid;
        kpf[i] = *(const bf16x8*)(kp + ch * 8);
        vpf[i] = *(const bf16x8*)(vp + (ch >> 3) * S_ + (ch & 7) * 8);
    }

    for (int ti = 0; ti < nt; ++ti) {
        __syncthreads();   // prior tile's LDS reads done
        #pragma unroll
        for (int i = 0; i < 4; ++i) {
            const int ch = i * 256 + tid;
            *(bf16x8*)(&lds_k[(ch >> 4) * LDK + (ch & 15) * 8]) = kpf[i];
            *(bf16x8*)(&lds_v[(ch >> 3) * LDV + (ch & 7) * 8]) = vpf[i];
        }
        __syncthreads();
        if (ti + 1 < nt) {   // prefetch next tile (waited at next iter's writes)
            kp += 64 * D_;
            vp += 64;
            #pragma unroll
            for (int i = 0; i < 4; ++i) {
                const int ch = i * 256 + tid;
                kpf[i] = *(const bf16x8*)(kp + ch * 8);
                vpf[i] = *(const bf16x8*)(vp + (ch >> 3) * S_ + (ch & 7) * 8);
            }
        }

        const int t0 = ti * BN;
        if (t0 > wr + 31) continue;   // wave-uniform: tile fully masked for this wave

        // ---- S = Q K^T ----
        f32x4 sc[2][4];
        #pragma unroll
        for (int mb = 0; mb < 2; ++mb)
            #pragma unroll
            for (int nb = 0; nb < 4; ++nb) sc[mb][nb] = (f32x4){0.f, 0.f, 0.f, 0.f};
        #pragma unroll
        for (int c = 0; c < 4; ++c) {
            #pragma unroll
            for (int nb = 0; nb < 4; ++nb) {
                bf16x8 kf = *(const bf16x8*)(&lds_k[(nb * 16 + l16) * LDK + c * 32 + quad * 8]);
                sc[0][nb] = __builtin_amdgcn_mfma_f32_16x16x32_bf16(qf[0][c], kf, sc[0][nb], 0, 0, 0);
                sc[1][nb] = __builtin_amdgcn_mfma_f32_16x16x32_bf16(qf[1][c], kf, sc[1][nb], 0, 0, 0);
            }
        }

        // ---- online softmax (exp2 units) ----
        const bool needmask = (t0 + BN - 1 > wr);
        #pragma unroll
        for (int mb = 0; mb < 2; ++mb)
            #pragma unroll
            for (int nb = 0; nb < 4; ++nb)
                #pragma unroll
                for (int r = 0; r < 4; ++r) {
                    float z = sc[mb][nb][r] * sl2e;
                    if (needmask) {
                        const int tcol = t0 + nb * 16 + l16;
                        const int srow = wr + mb * 16 + quad * 4 + r;
                        if (tcol > srow) z = -1e30f;
                    }
                    sc[mb][nb][r] = z;
                }
        float alpha[2][4];
        #pragma unroll
        for (int mb = 0; mb < 2; ++mb)
            #pragma unroll
            for (int r = 0; r < 4; ++r) {
                float m = fmaxf(fmaxf(sc[mb][0][r], sc[mb][1][r]),
                                fmaxf(sc[mb][2][r], sc[mb][3][r]));
                m = fmaxf(m, __shfl_xor(m, 1, 16));
                m = fmaxf(m, __shfl_xor(m, 2, 16));
                m = fmaxf(m, __shfl_xor(m, 4, 16));
                m = fmaxf(m, __shfl_xor(m, 8, 16));
                const float mnew = fmaxf(Mr[mb][r], m);
                alpha[mb][r] = exp2f(Mr[mb][r] - mnew);
                Mr[mb][r] = mnew;
            }
        #pragma unroll
        for (int mb = 0; mb < 2; ++mb)
            #pragma unroll
            for (int nb = 0; nb < 4; ++nb)
                #pragma unroll
                for (int r = 0; r < 4; ++r)
                    sc[mb][nb][r] = exp2f(sc[mb][nb][r] - Mr[mb][r]);
        #pragma unroll
        for (int mb = 0; mb < 2; ++mb)
            #pragma unroll
            for (int r = 0; r < 4; ++r)
                Lr[mb][r] = Lr[mb][r] * alpha[mb][r] +
                            (sc[mb][0][r] + sc[mb][1][r] + sc[mb][2][r] + sc[mb][3][r]);
        // P -> wave-private LDS (C-layout write, A-layout read; no barrier needed)
        #pragma unroll
        for (int mb = 0; mb < 2; ++mb)
            #pragma unroll
            for (int nb = 0; nb < 4; ++nb)
                #pragma unroll
                for (int r = 0; r < 4; ++r)
                    pw[(mb * 16 + quad * 4 + r) * LDP + nb * 16 + l16] =
                        (short)f2bf(sc[mb][nb][r]);
        // rescale O
        #pragma unroll
        for (int mb = 0; mb < 2; ++mb)
            #pragma unroll
            for (int db = 0; db < 8; ++db)
                #pragma unroll
                for (int r = 0; r < 4; ++r) o[mb][db][r] *= alpha[mb][r];

        // ---- O += P V ----
        bf16x8 pf[2][2];
        #pragma unroll
        for (int mb = 0; mb < 2; ++mb)
            #pragma unroll
            for (int kk = 0; kk < 2; ++kk)
                pf[mb][kk] = *(const bf16x8*)(&pw[(mb * 16 + l16) * LDP + kk * 32 + quad * 8]);
        #pragma unroll
        for (int kk = 0; kk < 2; ++kk) {
            #pragma unroll
            for (int db = 0; db < 8; ++db) {
                bf16x8 vf = *(const bf16x8*)(&lds_v[(db * 16 + l16) * LDV + kk * 32 + quad * 8]);
                o[0][db] = __builtin_amdgcn_mfma_f32_16x16x32_bf16(pf[0][kk], vf, o[0][db], 0, 0, 0);
                o[1][db] = __builtin_amdgcn_mfma_f32_16x16x32_bf16(pf[1][kk], vf, o[1][db], 0, 0, 0);
            }
        }
    }

    // ---- epilogue ----
    #pragma unroll
    for (int mb = 0; mb < 2; ++mb)
        #pragma unroll
        for (int r = 0; r < 4; ++r) {
            float l = Lr[mb][r];
            l += __shfl_xor(l, 1, 16);
            l += __shfl_xor(l, 2, 16);
            l += __shfl_xor(l, 4, 16);
            l += __shfl_xor(l, 8, 16);
            Lr[mb][r] = 1.0f / l;
        }
    #pragma unroll
    for (int mb = 0; mb < 2; ++mb)
        #pragma unroll
        for (int r = 0; r < 4; ++r) {
            const int srow = wr + mb * 16 + quad * 4 + r;
            float* orow = out + (size_t)(b * S_ + srow) * (H_ * D_) + h * D_;
            #pragma unroll
            for (int db = 0; db < 8; ++db)
                orow[db * 16 + l16] = o[mb][db][r] * Lr[mb][r];
        }
}

extern "C" void kernel_launch(void* const* d_in, const int* in_sizes, int n_in,
                              void* d_out, int out_size, void* d_ws, size_t ws_size,
                              hipStream_t stream) {
    // inputs: input_pos, q, k, v, bsz, seqlen, mask, cache_k, cache_v
    const float* q = (const float*)d_in[1];
    const float* k = (const float*)d_in[2];
    const float* v = (const float*)d_in[3];
    float* out = (float*)d_out;
    short* kws = (short*)d_ws;                           // 8.39 MB
    short* vws = kws + (size_t)B_ * KVH_ * S_ * D_;      // 8.39 MB (V^T)

    conv_k<<<(B_ * KVH_ * S_ * D_) / (256 * 8), 256, 0, stream>>>(k, kws);
    conv_vt<<<dim3(D_ / 64, S_ / 64, B_ * KVH_), 256, 0, stream>>>(v, vws);
    fa_fwd<<<dim3(NQT, H_, B_), 256, 0, stream>>>(q, kws, vws, out);
}